// Round 4
// baseline (61.823 us; speedup 1.0000x reference)
//
#include <hip/hip_runtime.h>

#define SDIM 64
#define DDIM 128
#define HDIM 512

typedef __attribute__((ext_vector_type(8))) __bf16 bf16x8;
typedef __attribute__((ext_vector_type(4))) float f32x4;
typedef __attribute__((ext_vector_type(4))) float float4v;
typedef __attribute__((ext_vector_type(4))) unsigned int u32x4;

__device__ __forceinline__ unsigned short f2bfc(float f) {
    __bf16 h = (__bf16)f;
    return __builtin_bit_cast(unsigned short, h);
}
__device__ __forceinline__ float bf2f(unsigned short b) {
    union { unsigned int u; float f; } v; v.u = ((unsigned int)b) << 16;
    return v.f;
}

// swizzle on ushort index: XOR bits 3..5 with (row&7)  == byte ^= (row&7)<<4
#define SWZ(idx, row) ((idx) ^ (((row) & 7) << 3))

// ---------------------------------------------------------------------------
// Prep: transpose + fp32->bf16 convert the 4 weight matrices into ws.
// ws layout (ushort units): Wt1[512][128] @0, Wt2[128][512] @65536,
//                           Wt3[512][256] @131072, Wt4[128][512] @262144
// ---------------------------------------------------------------------------
__global__ __launch_bounds__(256) void kprep(
    const float* __restrict__ W1, const float* __restrict__ W2,
    const float* __restrict__ W3, const float* __restrict__ W4,
    unsigned short* __restrict__ ws) {
    __shared__ unsigned short tile[32][33];
    int b = blockIdx.x;
    const float* src; unsigned short* dst; int K, N, tr, tc;
    if (b < 64)        { src = W1; dst = ws;          K = 128; N = 512; int t = b;       tr = t >> 4; tc = t & 15; }
    else if (b < 128)  { src = W2; dst = ws + 65536;  K = 512; N = 128; int t = b - 64;  tr = t >> 2; tc = t & 3;  }
    else if (b < 256)  { src = W3; dst = ws + 131072; K = 256; N = 512; int t = b - 128; tr = t >> 4; tc = t & 15; }
    else               { src = W4; dst = ws + 262144; K = 512; N = 128; int t = b - 256; tr = t >> 2; tc = t & 3;  }
    int tid = threadIdx.x;
#pragma unroll
    for (int i = 0; i < 4; i++) {
        int e = tid + i * 256;
        int r = e >> 5, c = e & 31;
        tile[r][c] = f2bfc(src[(tr * 32 + r) * N + tc * 32 + c]);
    }
    __syncthreads();
#pragma unroll
    for (int i = 0; i < 4; i++) {
        int e = tid + i * 256;
        int r = e >> 5, c = e & 31;      // r: n-in-tile, c: k-in-tile
        dst[(tc * 32 + r) * K + tr * 32 + c] = tile[c][r];
    }
}

// ---------------------------------------------------------------------------
// Fused DeepSets block: grid 512 = (l, half). Each block: 32 rows of one l.
// 512 threads = 8 waves. LDS 56 KB -> 2 blocks/CU. B-fragments register-
// prefetched in batches so L2 latency is exposed ~8x/wave, not ~80x.
// ---------------------------------------------------------------------------
__global__ __launch_bounds__(512, 4) void kmain(
    const float* __restrict__ x,
    const float* __restrict__ b1, const float* __restrict__ b2,
    const float* __restrict__ b3, const float* __restrict__ b4,
    const unsigned short* __restrict__ ws, float* __restrict__ out) {

    __shared__ __align__(16) unsigned short xs[SDIM * DDIM];   // 16 KB
    __shared__ __align__(16) unsigned short cc[32 * DDIM];     //  8 KB (cs, later cm)
    __shared__ __align__(16) unsigned short h1[32 * HDIM];     // 32 KB (hidden / scratch / fp32 out-bounce)

    const unsigned short* Wt1 = ws;
    const unsigned short* Wt2 = ws + 65536;
    const unsigned short* Wt3 = ws + 131072;
    const unsigned short* Wt4 = ws + 262144;

    const int tid  = threadIdx.x;
    const int lane = tid & 63;
    const int wid  = tid >> 6;            // 0..7
    const int bx   = blockIdx.x;
    const int l    = bx >> 1;
    const int hf   = bx & 1;
    const int lr   = lane & 15;
    const int lk   = (lane >> 4) << 3;
    const int lq   = (lane >> 4) << 2;
    const float* xg = x + l * SDIM * DDIM;

    // max-phase scratch overlaid on h1
    float* pm1 = (float*)h1;
    float* pm2 = pm1 + 512;
    int*   pi1 = (int*)(pm2 + 512);
    float* fm1 = (float*)(pi1 + 512);
    float* fm2 = fm1 + 128;
    int*   fi  = (int*)(fm2 + 128);
    float* fbuf = (float*)h1;             // fp32 out bounce (32*128*4B = 16 KB)

    // ---- bias prefetch (latency hidden under stage+max phases) ----
    const int colw = wid * 64 + lr;       // + n*16
    const int ncol = wid * 16 + lr;
    float bias1[4], bias3[4];
#pragma unroll
    for (int n = 0; n < 4; n++) { bias1[n] = b1[colw + n * 16]; bias3[n] = b3[colw + n * 16]; }
    float bias2v = b2[ncol];
    float bias4v = b4[ncol];

    // ---- stage all 64 rows of x -> xs (bf16, swizzled) ----
#pragma unroll
    for (int it = 0; it < 2; it++) {
        int ch   = tid + it * 512;
        int base = ch * 8;
        int row  = base >> 7;
        float4v v0 = *(const float4v*)(xg + base);
        float4v v1 = *(const float4v*)(xg + base + 4);
        u32x4 p;
        p.x = (unsigned int)f2bfc(v0.x) | ((unsigned int)f2bfc(v0.y) << 16);
        p.y = (unsigned int)f2bfc(v0.z) | ((unsigned int)f2bfc(v0.w) << 16);
        p.z = (unsigned int)f2bfc(v1.x) | ((unsigned int)f2bfc(v1.y) << 16);
        p.w = (unsigned int)f2bfc(v1.z) | ((unsigned int)f2bfc(v1.w) << 16);
        *(u32x4*)(&xs[SWZ(base, row)]) = p;
    }
    __syncthreads();

    // ---- masked all-pairs max via top-2 ----
    {
        int d = tid & 127, q = tid >> 7;
        float m1 = -3.4e38f, m2 = -3.4e38f; int i1 = -1;
#pragma unroll
        for (int i = 0; i < 16; i++) {
            int row = q * 16 + i;
            float v = bf2f(xs[SWZ(row * DDIM + d, row)]);
            if (v > m1) { m2 = m1; m1 = v; i1 = row; }
            else if (v > m2) { m2 = v; }
        }
        pm1[q * 128 + d] = m1; pm2[q * 128 + d] = m2; pi1[q * 128 + d] = i1;
    }
    __syncthreads();
    if (tid < 128) {
        int d = tid;
        float m1 = pm1[d], m2 = pm2[d]; int i1 = pi1[d];
#pragma unroll
        for (int q = 1; q < 4; q++) {
            float a1 = pm1[q * 128 + d], a2 = pm2[q * 128 + d]; int ai = pi1[q * 128 + d];
            if (a1 > m1) { m2 = fmaxf(m1, a2); m1 = a1; i1 = ai; }
            else         { m2 = fmaxf(m2, a1); }
        }
        fm1[d] = m1; fm2[d] = m2; fi[d] = i1;
    }
    __syncthreads();
    {
        int jl = tid >> 4;
        int d0 = (tid & 15) * 8;
        int jg = hf * 32 + jl;
        unsigned short t8[8];
#pragma unroll
        for (int e = 0; e < 8; e++) {
            int d = d0 + e;
            float v = (jg == fi[d]) ? fm2[d] : fm1[d];
            t8[e] = f2bfc(fmaxf(v, 0.0f));
        }
        u32x4 p;
        p.x = (unsigned int)t8[0] | ((unsigned int)t8[1] << 16);
        p.y = (unsigned int)t8[2] | ((unsigned int)t8[3] << 16);
        p.z = (unsigned int)t8[4] | ((unsigned int)t8[5] << 16);
        p.w = (unsigned int)t8[6] | ((unsigned int)t8[7] << 16);
        *(u32x4*)(&cc[SWZ(jl * DDIM + d0, jl)]) = p;
    }
    __syncthreads();

    // ---- GEMM1: h1 = relu(cc[32x128] @ W1 + b1); 2 prefetch batches of 8 ----
    {
        f32x4 acc[2][4];
#pragma unroll
        for (int m = 0; m < 2; m++)
#pragma unroll
            for (int n = 0; n < 4; n++) acc[m][n] = (f32x4)0.0f;
#pragma unroll
        for (int h = 0; h < 2; h++) {
            bf16x8 bq[8];
#pragma unroll
            for (int j = 0; j < 2; j++)
#pragma unroll
                for (int n = 0; n < 4; n++)
                    bq[j * 4 + n] = *(const bf16x8*)(&Wt1[(colw + n * 16) * 128 + (h * 2 + j) * 32 + lk]);
#pragma unroll
            for (int j = 0; j < 2; j++) {
                int ks = h * 2 + j;
                bf16x8 a[2];
#pragma unroll
                for (int m = 0; m < 2; m++) {
                    int row = m * 16 + lr;
                    a[m] = *(const bf16x8*)(&cc[SWZ(row * DDIM + ks * 32 + lk, row)]);
                }
#pragma unroll
                for (int n = 0; n < 4; n++)
#pragma unroll
                    for (int m = 0; m < 2; m++)
                        acc[m][n] = __builtin_amdgcn_mfma_f32_16x16x32_bf16(a[m], bq[j * 4 + n], acc[m][n], 0, 0, 0);
            }
        }
#pragma unroll
        for (int n = 0; n < 4; n++) {
            int col = colw + n * 16;
#pragma unroll
            for (int m = 0; m < 2; m++)
#pragma unroll
                for (int r = 0; r < 4; r++) {
                    int row = m * 16 + lq + r;
                    h1[SWZ(row * HDIM + col, row)] = f2bfc(fmaxf(acc[m][n][r] + bias1[n], 0.0f));
                }
        }
    }
    __syncthreads();

    // ---- GEMM2: cm = h1[32x512] @ W2 + b2; prefetch all 16 B-frags ----
    {
        f32x4 acc[2];
        acc[0] = (f32x4)0.0f; acc[1] = (f32x4)0.0f;
        bf16x8 bq[16];
#pragma unroll
        for (int ks = 0; ks < 16; ks++)
            bq[ks] = *(const bf16x8*)(&Wt2[ncol * 512 + ks * 32 + lk]);
#pragma unroll
        for (int ks = 0; ks < 16; ks++) {
#pragma unroll
            for (int m = 0; m < 2; m++) {
                int row = m * 16 + lr;
                bf16x8 a = *(const bf16x8*)(&h1[SWZ(row * HDIM + ks * 32 + lk, row)]);
                acc[m] = __builtin_amdgcn_mfma_f32_16x16x32_bf16(a, bq[ks], acc[m], 0, 0, 0);
            }
        }
#pragma unroll
        for (int m = 0; m < 2; m++)
#pragma unroll
            for (int r = 0; r < 4; r++) {
                int row = m * 16 + lq + r;
                cc[SWZ(row * DDIM + ncol, row)] = f2bfc(acc[m][r] + bias2v);
            }
    }
    __syncthreads();

    // ---- GEMM3: h1 = relu([xs_own | cm][32x256] @ W3 + b3); 4 batches of 8 ----
    {
        f32x4 acc[2][4];
#pragma unroll
        for (int m = 0; m < 2; m++)
#pragma unroll
            for (int n = 0; n < 4; n++) acc[m][n] = (f32x4)0.0f;
#pragma unroll
        for (int h = 0; h < 4; h++) {
            bf16x8 bq[8];
#pragma unroll
            for (int j = 0; j < 2; j++)
#pragma unroll
                for (int n = 0; n < 4; n++)
                    bq[j * 4 + n] = *(const bf16x8*)(&Wt3[(colw + n * 16) * 256 + (h * 2 + j) * 32 + lk]);
#pragma unroll
            for (int j = 0; j < 2; j++) {
                int ks = h * 2 + j;
                bf16x8 a[2];
#pragma unroll
                for (int m = 0; m < 2; m++) {
                    int row = m * 16 + lr;
                    if (ks < 4) {
                        int gr = hf * 32 + row;
                        a[m] = *(const bf16x8*)(&xs[SWZ(gr * DDIM + ks * 32 + lk, gr)]);
                    } else {
                        a[m] = *(const bf16x8*)(&cc[SWZ(row * DDIM + (ks - 4) * 32 + lk, row)]);
                    }
                }
#pragma unroll
                for (int n = 0; n < 4; n++)
#pragma unroll
                    for (int m = 0; m < 2; m++)
                        acc[m][n] = __builtin_amdgcn_mfma_f32_16x16x32_bf16(a[m], bq[j * 4 + n], acc[m][n], 0, 0, 0);
            }
        }
#pragma unroll
        for (int n = 0; n < 4; n++) {
            int col = colw + n * 16;
#pragma unroll
            for (int m = 0; m < 2; m++)
#pragma unroll
                for (int r = 0; r < 4; r++) {
                    int row = m * 16 + lq + r;
                    h1[SWZ(row * HDIM + col, row)] = f2bfc(fmaxf(acc[m][n][r] + bias3[n], 0.0f));
                }
        }
    }
    __syncthreads();

    // ---- GEMM4: acc = h1[32x512] @ W4 + b4 (prefetch 16 B-frags) ----
    {
        f32x4 acc[2];
        acc[0] = (f32x4)0.0f; acc[1] = (f32x4)0.0f;
        bf16x8 bq[16];
#pragma unroll
        for (int ks = 0; ks < 16; ks++)
            bq[ks] = *(const bf16x8*)(&Wt4[ncol * 512 + ks * 32 + lk]);
#pragma unroll
        for (int ks = 0; ks < 16; ks++) {
#pragma unroll
            for (int m = 0; m < 2; m++) {
                int row = m * 16 + lr;
                bf16x8 a = *(const bf16x8*)(&h1[SWZ(row * HDIM + ks * 32 + lk, row)]);
                acc[m] = __builtin_amdgcn_mfma_f32_16x16x32_bf16(a, bq[ks], acc[m], 0, 0, 0);
            }
        }
        __syncthreads();                  // all h1 reads done; reuse as fp32 bounce
#pragma unroll
        for (int m = 0; m < 2; m++)
#pragma unroll
            for (int r = 0; r < 4; r++) {
                int row = m * 16 + lq + r;
                fbuf[row * DDIM + ncol] = acc[m][r] + bias4v;
            }
    }
    __syncthreads();

    // ---- coalesced residual + store: float4 in, float4 out ----
#pragma unroll
    for (int it = 0; it < 2; it++) {
        int f    = tid + it * 512;        // float4 index in [0,1024)
        int row  = f >> 5;                // local row 0..31
        int col0 = (f & 31) * 4;
        int gr   = hf * 32 + row;
        float4v h = *(const float4v*)(&fbuf[row * DDIM + col0]);
        float4v xv = *(const float4v*)(&xg[gr * DDIM + col0]);
        float4v o; o.x = h.x + xv.x; o.y = h.y + xv.y; o.z = h.z + xv.z; o.w = h.w + xv.w;
        *(float4v*)(&out[(l * SDIM + gr) * DDIM + col0]) = o;
    }
}

extern "C" void kernel_launch(void* const* d_in, const int* in_sizes, int n_in,
                              void* d_out, int out_size, void* d_ws, size_t ws_size,
                              hipStream_t stream) {
    const float* x  = (const float*)d_in[0];
    const float* W1 = (const float*)d_in[1];
    const float* b1 = (const float*)d_in[2];
    const float* W2 = (const float*)d_in[3];
    const float* b2 = (const float*)d_in[4];
    const float* W3 = (const float*)d_in[5];
    const float* b3 = (const float*)d_in[6];
    const float* W4 = (const float*)d_in[7];
    const float* b4 = (const float*)d_in[8];
    unsigned short* ws = (unsigned short*)d_ws;
    float* out = (float*)d_out;

    kprep<<<320, 256, 0, stream>>>(W1, W2, W3, W4, ws);
    kmain<<<512, 512, 0, stream>>>(x, b1, b2, b3, b4, ws, out);
}

// Round 5
// 50.397 us; speedup vs baseline: 1.2267x; 1.2267x over previous
//
#include <hip/hip_runtime.h>

#define SDIM 64
#define DDIM 128
#define HDIM 512

typedef __attribute__((ext_vector_type(8))) __bf16 bf16x8;
typedef __attribute__((ext_vector_type(4))) float f32x4;
typedef __attribute__((ext_vector_type(4))) float float4v;
typedef __attribute__((ext_vector_type(4))) unsigned int u32x4;

__device__ __forceinline__ unsigned short f2bfc(float f) {
    __bf16 h = (__bf16)f;
    return __builtin_bit_cast(unsigned short, h);
}

// swizzle on ushort index: XOR bits 3..5 with (row&7)  == byte ^= (row&7)<<4
#define SWZ(idx, row) ((idx) ^ (((row) & 7) << 3))

// block-wide barrier that does NOT drain vmcnt: LDS writes flushed (lgkmcnt),
// global prefetches stay in flight across the barrier.
__device__ __forceinline__ void bar_lds() {
    asm volatile("s_waitcnt lgkmcnt(0)" ::: "memory");
    __builtin_amdgcn_s_barrier();
    asm volatile("" ::: "memory");
}

// ---------------------------------------------------------------------------
// Prep: transpose + fp32->bf16 convert the 4 weight matrices into ws.
// ws layout (ushort units): Wt1[512][128] @0, Wt2[128][512] @65536,
//                           Wt3[512][256] @131072, Wt4[128][512] @262144
// ---------------------------------------------------------------------------
__global__ __launch_bounds__(256) void kprep(
    const float* __restrict__ W1, const float* __restrict__ W2,
    const float* __restrict__ W3, const float* __restrict__ W4,
    unsigned short* __restrict__ ws) {
    __shared__ unsigned short tile[32][33];
    int b = blockIdx.x;
    const float* src; unsigned short* dst; int K, N, tr, tc;
    if (b < 64)        { src = W1; dst = ws;          K = 128; N = 512; int t = b;       tr = t >> 4; tc = t & 15; }
    else if (b < 128)  { src = W2; dst = ws + 65536;  K = 512; N = 128; int t = b - 64;  tr = t >> 2; tc = t & 3;  }
    else if (b < 256)  { src = W3; dst = ws + 131072; K = 256; N = 512; int t = b - 128; tr = t >> 4; tc = t & 15; }
    else               { src = W4; dst = ws + 262144; K = 512; N = 128; int t = b - 256; tr = t >> 2; tc = t & 3;  }
    int tid = threadIdx.x;
#pragma unroll
    for (int i = 0; i < 4; i++) {
        int e = tid + i * 256;
        int r = e >> 5, c = e & 31;
        tile[r][c] = f2bfc(src[(tr * 32 + r) * N + tc * 32 + c]);
    }
    __syncthreads();
#pragma unroll
    for (int i = 0; i < 4; i++) {
        int e = tid + i * 256;
        int r = e >> 5, c = e & 31;
        dst[(tc * 32 + r) * K + tr * 32 + c] = tile[c][r];
    }
}

// ---------------------------------------------------------------------------
// Fused DeepSets block, phase-pipelined. grid 512 = (l, half); 256 thr = 4 waves.
// LDS 48KB. G1/G2 and G3/G4 interleaved in 128-wide chunks, one raw barrier
// per chunk; weight fragments register-prefetched one phase ahead.
// ---------------------------------------------------------------------------
__global__ __launch_bounds__(256, 2) void kmain(
    const float* __restrict__ x,
    const float* __restrict__ b1, const float* __restrict__ b2,
    const float* __restrict__ b3, const float* __restrict__ b4,
    const unsigned short* __restrict__ ws, float* __restrict__ out) {

    __shared__ __align__(16) unsigned char smem[49152];
    unsigned short* xs  = (unsigned short*)smem;             // 16KB [64][128]
    unsigned short* cs  = (unsigned short*)(smem + 16384);   //  8KB [32][128]
    unsigned short* hc0 = (unsigned short*)(smem + 24576);   //  8KB [32][128]
    unsigned short* hc1 = (unsigned short*)(smem + 32768);   //  8KB
    unsigned short* cmb = (unsigned short*)(smem + 40960);   //  8KB [32][128]
    // max-phase overlays (dead before their regions' first real use)
    float* pm1  = (float*)(smem + 16384);  // [16][128]
    float* pm2  = (float*)(smem + 24576);  // [16][128]
    int*   pi1  = (int*)  (smem + 32768);  // [16][128]
    float* l2m1 = (float*)(smem + 40960);  // [256]
    float* l2m2 = (float*)(smem + 41984);  // [256]
    int*   l2i  = (int*)  (smem + 43008);  // [256]
    float* fm1  = (float*)(smem + 44032);  // [128]
    float* fm2  = (float*)(smem + 44544);  // [128]
    int*   fi   = (int*)  (smem + 45056);  // [128]
    float* fbuf = (float*)smem;            // 16KB [32][128] fp32 (over xs, end)

    const unsigned short* Wt1 = ws;
    const unsigned short* Wt2 = ws + 65536;
    const unsigned short* Wt3 = ws + 131072;
    const unsigned short* Wt4 = ws + 262144;

    const int tid  = threadIdx.x;
    const int lane = tid & 63;
    const int wid  = tid >> 6;            // 0..3
    const int bx   = blockIdx.x;
    const int l    = bx >> 1;
    const int hf   = bx & 1;
    const int lr   = lane & 15;
    const int lk   = (lane >> 4) << 3;
    const int lq   = (lane >> 4) << 2;
    const float* xg = x + l * SDIM * DDIM;

    // ---------------- prologue: bias + first B-chunk prefetch ----------------
    float bias1v[8], bias3v[8];           // [c][n] (c*2+n)
#pragma unroll
    for (int c = 0; c < 4; c++)
#pragma unroll
        for (int n = 0; n < 2; n++) {
            bias1v[c * 2 + n] = b1[c * 128 + wid * 32 + n * 16 + lr];
            bias3v[c * 2 + n] = b3[c * 128 + wid * 32 + n * 16 + lr];
        }
    float bias2v[2], bias4v[2];
#pragma unroll
    for (int n = 0; n < 2; n++) {
        bias2v[n] = b2[wid * 32 + n * 16 + lr];
        bias4v[n] = b4[wid * 32 + n * 16 + lr];
    }
    bf16x8 b1f[8];                        // G1 B-frags, single-buffered
#pragma unroll
    for (int ks = 0; ks < 4; ks++)
#pragma unroll
        for (int n = 0; n < 2; n++)
            b1f[ks * 2 + n] = *(const bf16x8*)(&Wt1[(0 * 128 + wid * 32 + n * 16 + lr) * 128 + ks * 32 + lk]);

    // ---------------- phase 1: stage x -> xs + register top-2 ----------------
    const int rp   = tid >> 4;            // 0..15
    const int col0 = (tid & 15) * 8;
    {
        float m1[8], m2[8]; int i1[8];
#pragma unroll
        for (int e = 0; e < 8; e++) { m1[e] = -3.4e38f; m2[e] = -3.4e38f; i1[e] = -1; }
#pragma unroll
        for (int it = 0; it < 4; it++) {
            int row  = rp + it * 16;
            int base = row * DDIM + col0;
            float4v v0 = *(const float4v*)(xg + base);
            float4v v1 = *(const float4v*)(xg + base + 4);
            float v[8] = {v0.x, v0.y, v0.z, v0.w, v1.x, v1.y, v1.z, v1.w};
            unsigned short t8[8];
#pragma unroll
            for (int e = 0; e < 8; e++) {
                t8[e] = f2bfc(v[e]);
                float q = v[e];
                if (q > m1[e]) { m2[e] = m1[e]; m1[e] = q; i1[e] = row; }
                else if (q > m2[e]) { m2[e] = q; }
            }
            u32x4 p;
            p.x = (unsigned int)t8[0] | ((unsigned int)t8[1] << 16);
            p.y = (unsigned int)t8[2] | ((unsigned int)t8[3] << 16);
            p.z = (unsigned int)t8[4] | ((unsigned int)t8[5] << 16);
            p.w = (unsigned int)t8[6] | ((unsigned int)t8[7] << 16);
            *(u32x4*)(&xs[SWZ(base, row)]) = p;
        }
#pragma unroll
        for (int e = 0; e < 8; e++) {
            pm1[rp * 128 + col0 + e] = m1[e];
            pm2[rp * 128 + col0 + e] = m2[e];
            pi1[rp * 128 + col0 + e] = i1[e];
        }
    }
    bar_lds();

    // ---------------- phase 2: combine 16 partials -> 2 ----------------
    {
        int d = tid & 127, h = tid >> 7;
        float m1 = -3.4e38f, m2 = -3.4e38f; int i1 = -1;
#pragma unroll
        for (int r = 0; r < 8; r++) {
            int q = h * 8 + r;
            float a1 = pm1[q * 128 + d], a2 = pm2[q * 128 + d]; int ai = pi1[q * 128 + d];
            if (a1 > m1) { m2 = fmaxf(m1, a2); m1 = a1; i1 = ai; }
            else         { m2 = fmaxf(m2, a1); }
        }
        l2m1[h * 128 + d] = m1; l2m2[h * 128 + d] = m2; l2i[h * 128 + d] = i1;
    }
    bar_lds();

    // ---------------- phase 3: final top-2 ----------------
    if (tid < 128) {
        int d = tid;
        float m1 = l2m1[d], m2 = l2m2[d]; int i1 = l2i[d];
        float a1 = l2m1[128 + d], a2 = l2m2[128 + d]; int ai = l2i[128 + d];
        if (a1 > m1) { m2 = fmaxf(m1, a2); m1 = a1; i1 = ai; }
        else         { m2 = fmaxf(m2, a1); }
        fm1[d] = m1; fm2[d] = m2; fi[d] = i1;
    }
    bar_lds();

    // ---------------- phase 4: write cs (own 32 rows) ----------------
    {
        float vm1[8], vm2[8]; int vi[8];
#pragma unroll
        for (int e = 0; e < 8; e++) { vm1[e] = fm1[col0 + e]; vm2[e] = fm2[col0 + e]; vi[e] = fi[col0 + e]; }
#pragma unroll
        for (int h = 0; h < 2; h++) {
            int row = rp + h * 16;                 // local 0..31
            int jg  = hf * 32 + row;
            unsigned short t8[8];
#pragma unroll
            for (int e = 0; e < 8; e++) {
                float v = (jg == vi[e]) ? vm2[e] : vm1[e];
                t8[e] = f2bfc(fmaxf(v, 0.0f));
            }
            u32x4 p;
            p.x = (unsigned int)t8[0] | ((unsigned int)t8[1] << 16);
            p.y = (unsigned int)t8[2] | ((unsigned int)t8[3] << 16);
            p.z = (unsigned int)t8[4] | ((unsigned int)t8[5] << 16);
            p.w = (unsigned int)t8[6] | ((unsigned int)t8[7] << 16);
            *(u32x4*)(&cs[SWZ(row * DDIM + col0, row)]) = p;
        }
    }
    bar_lds();

    // ---------------- G1/G2 interleaved, 4 chunks of 128 ----------------
    f32x4 acc2[2][2];
#pragma unroll
    for (int m = 0; m < 2; m++) for (int n = 0; n < 2; n++) acc2[m][n] = (f32x4)0.0f;
    bf16x8 b2f[2][8];
    bf16x8 b3f[16];
#pragma unroll
    for (int c = 0; c < 4; c++) {
        // issue G2 B chunk c (used next phase)
#pragma unroll
        for (int ks = 0; ks < 4; ks++)
#pragma unroll
            for (int n = 0; n < 2; n++)
                b2f[c & 1][ks * 2 + n] = *(const bf16x8*)(&Wt2[(wid * 32 + n * 16 + lr) * 512 + c * 128 + ks * 32 + lk]);
        // G1 chunk c
        f32x4 acc1[2][2];
#pragma unroll
        for (int m = 0; m < 2; m++) for (int n = 0; n < 2; n++) acc1[m][n] = (f32x4)0.0f;
#pragma unroll
        for (int ks = 0; ks < 4; ks++) {
            bf16x8 a0 = *(const bf16x8*)(&cs[SWZ((lr) * DDIM + ks * 32 + lk, lr)]);
            bf16x8 a1 = *(const bf16x8*)(&cs[SWZ((16 + lr) * DDIM + ks * 32 + lk, 16 + lr)]);
#pragma unroll
            for (int n = 0; n < 2; n++) {
                acc1[0][n] = __builtin_amdgcn_mfma_f32_16x16x32_bf16(a0, b1f[ks * 2 + n], acc1[0][n], 0, 0, 0);
                acc1[1][n] = __builtin_amdgcn_mfma_f32_16x16x32_bf16(a1, b1f[ks * 2 + n], acc1[1][n], 0, 0, 0);
            }
        }
        // post-use: prefetch G1 B chunk c+1 / G3 B chunk 0
        if (c < 3) {
#pragma unroll
            for (int ks = 0; ks < 4; ks++)
#pragma unroll
                for (int n = 0; n < 2; n++)
                    b1f[ks * 2 + n] = *(const bf16x8*)(&Wt1[((c + 1) * 128 + wid * 32 + n * 16 + lr) * 128 + ks * 32 + lk]);
        } else {
#pragma unroll
            for (int ks = 0; ks < 8; ks++)
#pragma unroll
                for (int n = 0; n < 2; n++)
                    b3f[ks * 2 + n] = *(const bf16x8*)(&Wt3[(0 * 128 + wid * 32 + n * 16 + lr) * 256 + ks * 32 + lk]);
        }
        // G1 epilogue -> hc[c&1]
        {
            unsigned short* hw = (c & 1) ? hc1 : hc0;
#pragma unroll
            for (int n = 0; n < 2; n++)
#pragma unroll
                for (int m = 0; m < 2; m++)
#pragma unroll
                    for (int r = 0; r < 4; r++) {
                        int row = m * 16 + lq + r;
                        hw[SWZ(row * DDIM + wid * 32 + n * 16 + lr, row)] =
                            f2bfc(fmaxf(acc1[m][n][r] + bias1v[c * 2 + n], 0.0f));
                    }
        }
        // G2 chunk c-1 from hc[(c-1)&1]
        if (c > 0) {
            const unsigned short* hr = ((c - 1) & 1) ? hc1 : hc0;
#pragma unroll
            for (int ks = 0; ks < 4; ks++) {
                bf16x8 a0 = *(const bf16x8*)(&hr[SWZ((lr) * DDIM + ks * 32 + lk, lr)]);
                bf16x8 a1 = *(const bf16x8*)(&hr[SWZ((16 + lr) * DDIM + ks * 32 + lk, 16 + lr)]);
#pragma unroll
                for (int n = 0; n < 2; n++) {
                    acc2[0][n] = __builtin_amdgcn_mfma_f32_16x16x32_bf16(a0, b2f[(c - 1) & 1][ks * 2 + n], acc2[0][n], 0, 0, 0);
                    acc2[1][n] = __builtin_amdgcn_mfma_f32_16x16x32_bf16(a1, b2f[(c - 1) & 1][ks * 2 + n], acc2[1][n], 0, 0, 0);
                }
            }
        }
        bar_lds();
    }
    // tail: G2 chunk 3 + cm epilogue; prefetch G4 B chunk 0
    bf16x8 b4f[2][8];
#pragma unroll
    for (int ks = 0; ks < 4; ks++)
#pragma unroll
        for (int n = 0; n < 2; n++)
            b4f[0][ks * 2 + n] = *(const bf16x8*)(&Wt4[(wid * 32 + n * 16 + lr) * 512 + 0 * 128 + ks * 32 + lk]);
    {
        const unsigned short* hr = hc1;   // chunk 3 parity
#pragma unroll
        for (int ks = 0; ks < 4; ks++) {
            bf16x8 a0 = *(const bf16x8*)(&hr[SWZ((lr) * DDIM + ks * 32 + lk, lr)]);
            bf16x8 a1 = *(const bf16x8*)(&hr[SWZ((16 + lr) * DDIM + ks * 32 + lk, 16 + lr)]);
#pragma unroll
            for (int n = 0; n < 2; n++) {
                acc2[0][n] = __builtin_amdgcn_mfma_f32_16x16x32_bf16(a0, b2f[1][ks * 2 + n], acc2[0][n], 0, 0, 0);
                acc2[1][n] = __builtin_amdgcn_mfma_f32_16x16x32_bf16(a1, b2f[1][ks * 2 + n], acc2[1][n], 0, 0, 0);
            }
        }
#pragma unroll
        for (int n = 0; n < 2; n++)
#pragma unroll
            for (int m = 0; m < 2; m++)
#pragma unroll
                for (int r = 0; r < 4; r++) {
                    int row = m * 16 + lq + r;
                    cmb[SWZ(row * DDIM + wid * 32 + n * 16 + lr, row)] = f2bfc(acc2[m][n][r] + bias2v[n]);
                }
    }
    bar_lds();

    // ---------------- G3/G4 interleaved, 4 chunks of 128 ----------------
    f32x4 acc4[2][2];
#pragma unroll
    for (int m = 0; m < 2; m++) for (int n = 0; n < 2; n++) acc4[m][n] = (f32x4)0.0f;
    float4v xr[4];
#pragma unroll
    for (int c = 0; c < 4; c++) {
        if (c > 0) {   // G4 B chunk c (used next phase)
#pragma unroll
            for (int ks = 0; ks < 4; ks++)
#pragma unroll
                for (int n = 0; n < 2; n++)
                    b4f[c & 1][ks * 2 + n] = *(const bf16x8*)(&Wt4[(wid * 32 + n * 16 + lr) * 512 + c * 128 + ks * 32 + lk]);
        }
        // G3 chunk c: A = [xs(own rows) | cm], K=256
        f32x4 acc3[2][2];
#pragma unroll
        for (int m = 0; m < 2; m++) for (int n = 0; n < 2; n++) acc3[m][n] = (f32x4)0.0f;
#pragma unroll
        for (int ks = 0; ks < 8; ks++) {
            bf16x8 a0, a1;
            if (ks < 4) {
                int g0 = hf * 32 + lr, g1 = hf * 32 + 16 + lr;
                a0 = *(const bf16x8*)(&xs[SWZ(g0 * DDIM + ks * 32 + lk, g0)]);
                a1 = *(const bf16x8*)(&xs[SWZ(g1 * DDIM + ks * 32 + lk, g1)]);
            } else {
                a0 = *(const bf16x8*)(&cmb[SWZ((lr) * DDIM + (ks - 4) * 32 + lk, lr)]);
                a1 = *(const bf16x8*)(&cmb[SWZ((16 + lr) * DDIM + (ks - 4) * 32 + lk, 16 + lr)]);
            }
#pragma unroll
            for (int n = 0; n < 2; n++) {
                acc3[0][n] = __builtin_amdgcn_mfma_f32_16x16x32_bf16(a0, b3f[ks * 2 + n], acc3[0][n], 0, 0, 0);
                acc3[1][n] = __builtin_amdgcn_mfma_f32_16x16x32_bf16(a1, b3f[ks * 2 + n], acc3[1][n], 0, 0, 0);
            }
        }
        // post-use: prefetch G3 B chunk c+1; residual x at c==2
        if (c < 3) {
#pragma unroll
            for (int ks = 0; ks < 8; ks++)
#pragma unroll
                for (int n = 0; n < 2; n++)
                    b3f[ks * 2 + n] = *(const bf16x8*)(&Wt3[((c + 1) * 128 + wid * 32 + n * 16 + lr) * 256 + ks * 32 + lk]);
        }
        if (c == 2) {
#pragma unroll
            for (int i = 0; i < 4; i++) {
                int e = tid + i * 256;
                int row = e >> 5, cc0 = (e & 31) * 4;
                xr[i] = *(const float4v*)(&xg[(hf * 32 + row) * DDIM + cc0]);
            }
        }
        // G3 epilogue -> hc[c&1]
        {
            unsigned short* hw = (c & 1) ? hc1 : hc0;
#pragma unroll
            for (int n = 0; n < 2; n++)
#pragma unroll
                for (int m = 0; m < 2; m++)
#pragma unroll
                    for (int r = 0; r < 4; r++) {
                        int row = m * 16 + lq + r;
                        hw[SWZ(row * DDIM + wid * 32 + n * 16 + lr, row)] =
                            f2bfc(fmaxf(acc3[m][n][r] + bias3v[c * 2 + n], 0.0f));
                    }
        }
        // G4 chunk c-1
        if (c > 0) {
            const unsigned short* hr = ((c - 1) & 1) ? hc1 : hc0;
#pragma unroll
            for (int ks = 0; ks < 4; ks++) {
                bf16x8 a0 = *(const bf16x8*)(&hr[SWZ((lr) * DDIM + ks * 32 + lk, lr)]);
                bf16x8 a1 = *(const bf16x8*)(&hr[SWZ((16 + lr) * DDIM + ks * 32 + lk, 16 + lr)]);
#pragma unroll
                for (int n = 0; n < 2; n++) {
                    acc4[0][n] = __builtin_amdgcn_mfma_f32_16x16x32_bf16(a0, b4f[(c - 1) & 1][ks * 2 + n], acc4[0][n], 0, 0, 0);
                    acc4[1][n] = __builtin_amdgcn_mfma_f32_16x16x32_bf16(a1, b4f[(c - 1) & 1][ks * 2 + n], acc4[1][n], 0, 0, 0);
                }
            }
        }
        bar_lds();
    }
    // tail: G4 chunk 3, write fp32 to fbuf (over dead xs region)
    {
        const unsigned short* hr = hc1;
#pragma unroll
        for (int ks = 0; ks < 4; ks++) {
            bf16x8 a0 = *(const bf16x8*)(&hr[SWZ((lr) * DDIM + ks * 32 + lk, lr)]);
            bf16x8 a1 = *(const bf16x8*)(&hr[SWZ((16 + lr) * DDIM + ks * 32 + lk, 16 + lr)]);
#pragma unroll
            for (int n = 0; n < 2; n++) {
                acc4[0][n] = __builtin_amdgcn_mfma_f32_16x16x32_bf16(a0, b4f[1][ks * 2 + n], acc4[0][n], 0, 0, 0);
                acc4[1][n] = __builtin_amdgcn_mfma_f32_16x16x32_bf16(a1, b4f[1][ks * 2 + n], acc4[1][n], 0, 0, 0);
            }
        }
#pragma unroll
        for (int n = 0; n < 2; n++)
#pragma unroll
            for (int m = 0; m < 2; m++)
#pragma unroll
                for (int r = 0; r < 4; r++) {
                    int row = m * 16 + lq + r;
                    fbuf[row * DDIM + wid * 32 + n * 16 + lr] = acc4[m][n][r] + bias4v[n];
                }
    }
    bar_lds();

    // ---------------- coalesced residual + store ----------------
#pragma unroll
    for (int i = 0; i < 4; i++) {
        int e = tid + i * 256;
        int row = e >> 5, cc0 = (e & 31) * 4;
        int gr  = hf * 32 + row;
        float4v h = *(const float4v*)(&fbuf[row * DDIM + cc0]);
        float4v o; o.x = h.x + xr[i].x; o.y = h.y + xr[i].y; o.z = h.z + xr[i].z; o.w = h.w + xr[i].w;
        *(float4v*)(&out[(l * SDIM + gr) * DDIM + cc0]) = o;
    }
}

extern "C" void kernel_launch(void* const* d_in, const int* in_sizes, int n_in,
                              void* d_out, int out_size, void* d_ws, size_t ws_size,
                              hipStream_t stream) {
    const float* x  = (const float*)d_in[0];
    const float* W1 = (const float*)d_in[1];
    const float* b1 = (const float*)d_in[2];
    const float* W2 = (const float*)d_in[3];
    const float* b2 = (const float*)d_in[4];
    const float* W3 = (const float*)d_in[5];
    const float* b3 = (const float*)d_in[6];
    const float* W4 = (const float*)d_in[7];
    const float* b4 = (const float*)d_in[8];
    unsigned short* ws = (unsigned short*)d_ws;
    float* out = (float*)d_out;

    kprep<<<320, 256, 0, stream>>>(W1, W2, W3, W4, ws);
    kmain<<<512, 256, 0, stream>>>(x, b1, b2, b3, b4, ws, out);
}

// Round 6
// 32.787 us; speedup vs baseline: 1.8856x; 1.5371x over previous
//
#include <hip/hip_runtime.h>

typedef __attribute__((ext_vector_type(8))) __bf16 bf16x8;
typedef __attribute__((ext_vector_type(4))) float f32x4;
typedef __attribute__((ext_vector_type(4))) float float4v;
typedef __attribute__((ext_vector_type(4))) unsigned int u32x4;
typedef __attribute__((ext_vector_type(4))) int i32x4;

__device__ __forceinline__ unsigned short f2bfc(float f) {
    __bf16 h = (__bf16)f;
    return __builtin_bit_cast(unsigned short, h);
}

// swizzle on ushort index: XOR bits 3..5 with (row&7)  == byte ^= (row&7)<<4
#define SWZ(idx, row) ((idx) ^ (((row) & 7) << 3))

// async global->LDS, 16B per lane; LDS dest = wave-uniform base + lane*16
__device__ __forceinline__ void gload_lds16(const unsigned short* g, unsigned short* l) {
    __builtin_amdgcn_global_load_lds(
        (const __attribute__((address_space(1))) unsigned int*)g,
        (__attribute__((address_space(3))) unsigned int*)l, 16, 0, 0);
}

// ---------------------------------------------------------------------------
// kprep v2: build the 20-chunk LDS image of all weights in ws.
// Chunk = 16384 ushorts (32KB) = [col 0..127][k 0..127] bf16, transposed from W,
// with the (col&7)<<3 ushort-index XOR swizzle BAKED IN so kmain staging is a
// pure linear copy. Chunks: 0-3 W1 (N-chunks), 4-7 W2 (K-chunks),
// 8-15 W3 (nc,kh), 16-19 W4 (K-chunks).
// ---------------------------------------------------------------------------
__global__ __launch_bounds__(256) void kprep(
    const float* __restrict__ W1, const float* __restrict__ W2,
    const float* __restrict__ W3, const float* __restrict__ W4,
    unsigned short* __restrict__ ws) {
    int g  = blockIdx.x * 256 + threadIdx.x;     // one u32 (2 bf16) per thread
    int u2 = g * 2;                              // ushort index
    int chunk = u2 >> 14;
    int us    = u2 & 16383;
    int col   = us >> 7;
    int kk    = (us & 127) ^ ((col & 7) << 3);   // unswizzle -> source k (even)
    const float* W; int kbase, nbase, ld;
    if (chunk < 4)       { W = W1; kbase = 0;                 nbase = chunk * 128;      ld = 512; }
    else if (chunk < 8)  { W = W2; kbase = (chunk - 4) * 128; nbase = 0;                ld = 128; }
    else if (chunk < 16) { int cc = chunk - 8;
                           W = W3; kbase = (cc & 1) * 128;    nbase = (cc >> 1) * 128;  ld = 512; }
    else                 { W = W4; kbase = (chunk - 16) * 128; nbase = 0;               ld = 128; }
    int k = kbase + kk, n = nbase + col;
    unsigned int lo = f2bfc(W[k * ld + n]);
    unsigned int hi = f2bfc(W[(k + 1) * ld + n]);
    ((unsigned int*)ws)[g] = lo | (hi << 16);
}

// stage one 32KB chunk: 8 waves x 4 iters x 1KB
__device__ __forceinline__ void stage_chunk(const unsigned short* __restrict__ wsrc,
                                            unsigned short* wdst, int wid, int lane) {
#pragma unroll
    for (int j = 0; j < 4; j++) {
        int ub = wid * 2048 + j * 512;           // ushort offset (wave-uniform)
        gload_lds16(wsrc + ub + lane * 8, wdst + ub);
    }
}

__device__ __forceinline__ void mfma_chunk(
    const unsigned short* __restrict__ A, int astride, int akoff,
    const unsigned short* __restrict__ W,
    int lr, int lk, int wm, int wn, f32x4 (&acc)[2][2]) {
#pragma unroll
    for (int ks = 0; ks < 4; ks++) {
        bf16x8 a[2], b[2];
#pragma unroll
        for (int m = 0; m < 2; m++) {
            int row = wm * 32 + m * 16 + lr;
            a[m] = *(const bf16x8*)(&A[SWZ(row * astride + akoff + ks * 32 + lk, row)]);
        }
#pragma unroll
        for (int n = 0; n < 2; n++) {
            int col = wn * 32 + n * 16 + lr;
            b[n] = *(const bf16x8*)(&W[SWZ(col * 128 + ks * 32 + lk, col)]);
        }
#pragma unroll
        for (int m = 0; m < 2; m++)
#pragma unroll
            for (int n = 0; n < 2; n++)
                acc[m][n] = __builtin_amdgcn_mfma_f32_16x16x32_bf16(a[m], b[n], acc[m][n], 0, 0, 0);
    }
}

template<bool RELU>
__device__ __forceinline__ void epi_store(unsigned short* dst, int dstride, int colbase,
                                          const f32x4 (&acc)[2][2], const float (&bias)[2],
                                          int lr, int lq, int wm, int wn) {
#pragma unroll
    for (int n = 0; n < 2; n++) {
        int col = colbase + wn * 32 + n * 16 + lr;
#pragma unroll
        for (int m = 0; m < 2; m++)
#pragma unroll
            for (int r = 0; r < 4; r++) {
                int row = wm * 32 + m * 16 + lq + r;
                float v = acc[m][n][r] + bias[n];
                if (RELU) v = fmaxf(v, 0.0f);
                dst[SWZ(row * dstride + col, row)] = f2bfc(v);
            }
    }
}

// ---------------------------------------------------------------------------
// kmain: one block per l (64 rows), 512 threads (8 waves = 2m x 4n grid).
// 160KB LDS: h1 64K | xs 16K | cmb 16K | wbuf 2x32K. Sequential GEMMs over
// 20 uniform 32KB weight-chunk phases, double-buffered via global_load_lds.
// ---------------------------------------------------------------------------
__global__ __launch_bounds__(512, 2) void kmain(
    const float* __restrict__ x,
    const float* __restrict__ b1, const float* __restrict__ b2,
    const float* __restrict__ b3, const float* __restrict__ b4,
    const unsigned short* __restrict__ ws, float* __restrict__ out) {

    __shared__ __align__(16) unsigned char smem[163840];
    unsigned short* h1  = (unsigned short*)smem;             // 64KB [64][512]
    unsigned short* xs  = (unsigned short*)(smem + 65536);   // 16KB [64][128]
    unsigned short* cmb = (unsigned short*)(smem + 81920);   // 16KB [64][128]
    unsigned short* wb0 = (unsigned short*)(smem + 98304);   // 32KB
    unsigned short* wb1 = (unsigned short*)(smem + 131072);  // 32KB
    // overlays (dead before regions' first real use)
    float* pm1  = (float*)smem;                // [32][128] in h1
    float* pm2  = pm1 + 4096;
    int*   pi1  = (int*)(pm2 + 4096);
    float* l2m1 = (float*)(smem + 49152);      // [4][128] in h1
    float* l2m2 = l2m1 + 512;
    int*   l2i  = (int*)(l2m2 + 512);
    float* fm1  = (float*)(smem + 81920);      // [128] in cmb (dead before cmb)
    float* fm2  = fm1 + 128;
    int*   fi   = (int*)(fm2 + 128);
    float* fbuf = (float*)(smem + 98304);      // [64][128] fp32 in wb0 (phase 19)

    const int tid  = threadIdx.x;
    const int lane = tid & 63;
    const int wid  = tid >> 6;                 // 0..7
    const int wm   = wid >> 2;                 // 0..1 (M half)
    const int wn   = wid & 3;                  // 0..3 (N quarter)
    const int l    = blockIdx.x;
    const int lr   = lane & 15;
    const int lk   = (lane >> 4) << 3;
    const int lq   = (lane >> 4) << 2;
    const float* xg = x + l * 64 * 128;

    // ---- prologue: kick stage of chunk 0; bias prefetch ----
    stage_chunk(ws, wb0, wid, lane);
    float bias1v[8], bias3v[8], bias2v[2], bias4v[2];
#pragma unroll
    for (int c = 0; c < 4; c++)
#pragma unroll
        for (int n = 0; n < 2; n++) {
            bias1v[c * 2 + n] = b1[c * 128 + wn * 32 + n * 16 + lr];
            bias3v[c * 2 + n] = b3[c * 128 + wn * 32 + n * 16 + lr];
        }
#pragma unroll
    for (int n = 0; n < 2; n++) {
        bias2v[n] = b2[wn * 32 + n * 16 + lr];
        bias4v[n] = b4[wn * 32 + n * 16 + lr];
    }

    // ---- P0: stage x -> xs (bf16, swizzled) + register top-2 over 2 rows ----
    const int rp   = tid >> 4;                 // 0..31
    const int col0 = (tid & 15) * 8;
    {
        float m1[8], m2[8]; int i1[8];
#pragma unroll
        for (int e = 0; e < 8; e++) { m1[e] = -3.4e38f; m2[e] = -3.4e38f; i1[e] = -1; }
#pragma unroll
        for (int it = 0; it < 2; it++) {
            int row  = rp + it * 32;
            int base = row * 128 + col0;
            float4v v0 = *(const float4v*)(xg + base);
            float4v v1 = *(const float4v*)(xg + base + 4);
            float v[8] = {v0.x, v0.y, v0.z, v0.w, v1.x, v1.y, v1.z, v1.w};
            unsigned short t8[8];
#pragma unroll
            for (int e = 0; e < 8; e++) {
                t8[e] = f2bfc(v[e]);
                if (v[e] > m1[e]) { m2[e] = m1[e]; m1[e] = v[e]; i1[e] = row; }
                else if (v[e] > m2[e]) { m2[e] = v[e]; }
            }
            u32x4 p;
            p.x = (unsigned)t8[0] | ((unsigned)t8[1] << 16);
            p.y = (unsigned)t8[2] | ((unsigned)t8[3] << 16);
            p.z = (unsigned)t8[4] | ((unsigned)t8[5] << 16);
            p.w = (unsigned)t8[6] | ((unsigned)t8[7] << 16);
            *(u32x4*)(&xs[SWZ(base, row)]) = p;
        }
#pragma unroll
        for (int h = 0; h < 2; h++) {
            float4v q1 = {m1[h*4+0], m1[h*4+1], m1[h*4+2], m1[h*4+3]};
            float4v q2 = {m2[h*4+0], m2[h*4+1], m2[h*4+2], m2[h*4+3]};
            i32x4  qi = {i1[h*4+0], i1[h*4+1], i1[h*4+2], i1[h*4+3]};
            *(float4v*)(&pm1[rp * 128 + col0 + h * 4]) = q1;
            *(float4v*)(&pm2[rp * 128 + col0 + h * 4]) = q2;
            *(i32x4*) (&pi1[rp * 128 + col0 + h * 4]) = qi;
        }
    }
    __syncthreads();

    // ---- P1: combine 32 partials -> 4 ----
    {
        int d = tid & 127, h = tid >> 7;       // h 0..3
        float m1 = -3.4e38f, m2 = -3.4e38f; int i1 = -1;
#pragma unroll
        for (int r = 0; r < 8; r++) {
            int q = h * 8 + r;
            float a1 = pm1[q * 128 + d], a2 = pm2[q * 128 + d]; int ai = pi1[q * 128 + d];
            if (a1 > m1) { m2 = fmaxf(m1, a2); m1 = a1; i1 = ai; }
            else         { m2 = fmaxf(m2, a1); }
        }
        l2m1[h * 128 + d] = m1; l2m2[h * 128 + d] = m2; l2i[h * 128 + d] = i1;
    }
    __syncthreads();

    // ---- P2: final top-2 -> fm1/fm2/fi ----
    if (tid < 128) {
        int d = tid;
        float m1 = l2m1[d], m2 = l2m2[d]; int i1 = l2i[d];
#pragma unroll
        for (int h = 1; h < 4; h++) {
            float a1 = l2m1[h * 128 + d], a2 = l2m2[h * 128 + d]; int ai = l2i[h * 128 + d];
            if (a1 > m1) { m2 = fmaxf(m1, a2); m1 = a1; i1 = ai; }
            else         { m2 = fmaxf(m2, a1); }
        }
        fm1[d] = m1; fm2[d] = m2; fi[d] = i1;
    }
    __syncthreads();

    // ---- build G1 A-fragments in registers from (fm1, fm2, fi) ----
    bf16x8 a1f[2][4];
#pragma unroll
    for (int ks = 0; ks < 4; ks++) {
        int k0 = ks * 32 + lk;
        float4v v1a = *(const float4v*)(&fm1[k0]);
        float4v v1b = *(const float4v*)(&fm1[k0 + 4]);
        float4v v2a = *(const float4v*)(&fm2[k0]);
        float4v v2b = *(const float4v*)(&fm2[k0 + 4]);
        i32x4  ia  = *(const i32x4*)(&fi[k0]);
        i32x4  ib  = *(const i32x4*)(&fi[k0 + 4]);
        float v1[8] = {v1a.x, v1a.y, v1a.z, v1a.w, v1b.x, v1b.y, v1b.z, v1b.w};
        float v2[8] = {v2a.x, v2a.y, v2a.z, v2a.w, v2b.x, v2b.y, v2b.z, v2b.w};
        int   ii[8] = {ia.x, ia.y, ia.z, ia.w, ib.x, ib.y, ib.z, ib.w};
#pragma unroll
        for (int m = 0; m < 2; m++) {
            int j = wm * 32 + m * 16 + lr;
            unsigned short t8[8];
#pragma unroll
            for (int e = 0; e < 8; e++) {
                float s = (ii[e] == j) ? v2[e] : v1[e];
                t8[e] = f2bfc(fmaxf(s, 0.0f));
            }
            u32x4 p;
            p.x = (unsigned)t8[0] | ((unsigned)t8[1] << 16);
            p.y = (unsigned)t8[2] | ((unsigned)t8[3] << 16);
            p.z = (unsigned)t8[4] | ((unsigned)t8[5] << 16);
            p.w = (unsigned)t8[6] | ((unsigned)t8[7] << 16);
            a1f[m][ks] = __builtin_bit_cast(bf16x8, p);
        }
    }

    // ---- G1: chunks 0..3, A from registers ----
#pragma unroll
    for (int c = 0; c < 4; c++) {
        stage_chunk(ws + (c + 1) * 16384, ((c + 1) & 1) ? wb1 : wb0, wid, lane);
        const unsigned short* wcur = (c & 1) ? wb1 : wb0;
        f32x4 acc[2][2];
#pragma unroll
        for (int m = 0; m < 2; m++) { acc[m][0] = (f32x4)0.0f; acc[m][1] = (f32x4)0.0f; }
#pragma unroll
        for (int ks = 0; ks < 4; ks++) {
            bf16x8 b[2];
#pragma unroll
            for (int n = 0; n < 2; n++) {
                int col = wn * 32 + n * 16 + lr;
                b[n] = *(const bf16x8*)(&wcur[SWZ(col * 128 + ks * 32 + lk, col)]);
            }
#pragma unroll
            for (int m = 0; m < 2; m++)
#pragma unroll
                for (int n = 0; n < 2; n++)
                    acc[m][n] = __builtin_amdgcn_mfma_f32_16x16x32_bf16(a1f[m][ks], b[n], acc[m][n], 0, 0, 0);
        }
        float bc[2] = {bias1v[c * 2 + 0], bias1v[c * 2 + 1]};
        epi_store<true>(h1, 512, c * 128, acc, bc, lr, lq, wm, wn);
        __syncthreads();
    }

    // ---- G2: chunks 4..7, A = h1 K-chunks, acc persists; tail -> cmb ----
    {
        f32x4 acc[2][2];
#pragma unroll
        for (int m = 0; m < 2; m++) { acc[m][0] = (f32x4)0.0f; acc[m][1] = (f32x4)0.0f; }
#pragma unroll
        for (int c = 0; c < 4; c++) {
            int ch = 4 + c;
            stage_chunk(ws + (ch + 1) * 16384, ((ch + 1) & 1) ? wb1 : wb0, wid, lane);
            const unsigned short* wcur = (ch & 1) ? wb1 : wb0;
            mfma_chunk(h1, 512, c * 128, wcur, lr, lk, wm, wn, acc);
            if (c == 3) epi_store<false>(cmb, 128, 0, acc, bias2v, lr, lq, wm, wn);
            __syncthreads();
        }
    }

    // ---- G3: chunks 8..15 (nc, kh): A = xs | cmb ----
#pragma unroll
    for (int nc = 0; nc < 4; nc++) {
        f32x4 acc[2][2];
#pragma unroll
        for (int m = 0; m < 2; m++) { acc[m][0] = (f32x4)0.0f; acc[m][1] = (f32x4)0.0f; }
        {
            int ch = 8 + nc * 2;
            stage_chunk(ws + (ch + 1) * 16384, ((ch + 1) & 1) ? wb1 : wb0, wid, lane);
            const unsigned short* wcur = (ch & 1) ? wb1 : wb0;
            mfma_chunk(xs, 128, 0, wcur, lr, lk, wm, wn, acc);
            __syncthreads();
        }
        {
            int ch = 9 + nc * 2;
            stage_chunk(ws + (ch + 1) * 16384, ((ch + 1) & 1) ? wb1 : wb0, wid, lane);
            const unsigned short* wcur = (ch & 1) ? wb1 : wb0;
            mfma_chunk(cmb, 128, 0, wcur, lr, lk, wm, wn, acc);
            float bc[2] = {bias3v[nc * 2 + 0], bias3v[nc * 2 + 1]};
            epi_store<true>(h1, 512, nc * 128, acc, bc, lr, lq, wm, wn);
            __syncthreads();
        }
    }

    // ---- G4: chunks 16..19, A = h1 K-chunks; tail -> fbuf (fp32, in wb0) ----
    {
        f32x4 acc[2][2];
#pragma unroll
        for (int m = 0; m < 2; m++) { acc[m][0] = (f32x4)0.0f; acc[m][1] = (f32x4)0.0f; }
        float4v xr[4];
#pragma unroll
        for (int c = 0; c < 4; c++) {
            int ch = 16 + c;
            if (ch < 19)
                stage_chunk(ws + (ch + 1) * 16384, ((ch + 1) & 1) ? wb1 : wb0, wid, lane);
            if (c == 3) {
#pragma unroll
                for (int it = 0; it < 4; it++) {
                    int f = tid + it * 512;
                    xr[it] = *(const float4v*)(&xg[(f >> 5) * 128 + (f & 31) * 4]);
                }
            }
            const unsigned short* wcur = (ch & 1) ? wb1 : wb0;
            mfma_chunk(h1, 512, c * 128, wcur, lr, lk, wm, wn, acc);
            if (c == 3) {
#pragma unroll
                for (int n = 0; n < 2; n++) {
                    int col = wn * 32 + n * 16 + lr;
#pragma unroll
                    for (int m = 0; m < 2; m++)
#pragma unroll
                        for (int r = 0; r < 4; r++) {
                            int row = wm * 32 + m * 16 + lq + r;
                            fbuf[row * 128 + col] = acc[m][n][r] + bias4v[n];
                        }
                }
            }
            __syncthreads();
        }
        // ---- coalesced residual + fp32 store ----
#pragma unroll
        for (int it = 0; it < 4; it++) {
            int f = tid + it * 512;
            int row = f >> 5, c0 = (f & 31) * 4;
            float4v h = *(const float4v*)(&fbuf[row * 128 + c0]);
            float4v o;
            o.x = h.x + xr[it].x; o.y = h.y + xr[it].y;
            o.z = h.z + xr[it].z; o.w = h.w + xr[it].w;
            *(float4v*)(&out[(l * 64 + row) * 128 + c0]) = o;
        }
    }
}

extern "C" void kernel_launch(void* const* d_in, const int* in_sizes, int n_in,
                              void* d_out, int out_size, void* d_ws, size_t ws_size,
                              hipStream_t stream) {
    const float* x  = (const float*)d_in[0];
    const float* W1 = (const float*)d_in[1];
    const float* b1 = (const float*)d_in[2];
    const float* W2 = (const float*)d_in[3];
    const float* b2 = (const float*)d_in[4];
    const float* W3 = (const float*)d_in[5];
    const float* b3 = (const float*)d_in[6];
    const float* W4 = (const float*)d_in[7];
    const float* b4 = (const float*)d_in[8];
    unsigned short* ws = (unsigned short*)d_ws;
    float* out = (float*)d_out;

    kprep<<<640, 256, 0, stream>>>(W1, W2, W3, W4, ws);
    kmain<<<256, 512, 0, stream>>>(x, b1, b2, b3, b4, ws, out);
}

// Round 7
// 32.230 us; speedup vs baseline: 1.9182x; 1.0173x over previous
//
#include <hip/hip_runtime.h>

typedef __attribute__((ext_vector_type(8))) __bf16 bf16x8;
typedef __attribute__((ext_vector_type(4))) float f32x4;
typedef __attribute__((ext_vector_type(4))) float float4v;
typedef __attribute__((ext_vector_type(4))) unsigned int u32x4;
typedef __attribute__((ext_vector_type(4))) int i32x4;

__device__ __forceinline__ unsigned short f2bfc(float f) {
    __bf16 h = (__bf16)f;
    return __builtin_bit_cast(unsigned short, h);
}

// swizzle on ushort index: XOR bits 3..5 with (row&7)
#define SWZ(idx, row) ((idx) ^ (((row) & 7) << 3))

// ---------------------------------------------------------------------------
// kprep v3: fragment-major weight image. One frag-unit = 1KB = 64 lanes x 16B,
// covering 16 cols x 32 k of W^T as an MFMA B-fragment (lane l: col=cb*16+(l&15),
// k=ks*32+(l>>4)*8 .. +7). Frag f at ws[f*512 ushorts]; addr = base+lane*16B is
// perfectly coalesced. Frag index within GEMM: cb*KS + ks.
// Bases (frags): G1=0(128), G2=128(128), G3=256(256), G4=512(128). Total 640KB.
// ---------------------------------------------------------------------------
__global__ __launch_bounds__(256) void kprep(
    const float* __restrict__ W1, const float* __restrict__ W2,
    const float* __restrict__ W3, const float* __restrict__ W4,
    unsigned short* __restrict__ ws) {
    int t = blockIdx.x * 256 + threadIdx.x;  // 40960 threads total
    int f = t >> 6;                          // frag 0..639
    int l = t & 63;
    int lr = l & 15, lkg = l >> 4;
    const float* W; int lg, KS, ld, ff;
    if (f < 128)      { W = W1; lg = 2; KS = 4;  ld = 512; ff = f; }
    else if (f < 256) { W = W2; lg = 4; KS = 16; ld = 128; ff = f - 128; }
    else if (f < 512) { W = W3; lg = 3; KS = 8;  ld = 512; ff = f - 256; }
    else              { W = W4; lg = 4; KS = 16; ld = 128; ff = f - 512; }
    int cb = ff >> lg, ks = ff & (KS - 1);
    int n = cb * 16 + lr, k = ks * 32 + lkg * 8;
    unsigned short t8[8];
#pragma unroll
    for (int e = 0; e < 8; e++) t8[e] = f2bfc(W[(k + e) * ld + n]);
    u32x4 p;
    p.x = (unsigned)t8[0] | ((unsigned)t8[1] << 16);
    p.y = (unsigned)t8[2] | ((unsigned)t8[3] << 16);
    p.z = (unsigned)t8[4] | ((unsigned)t8[5] << 16);
    p.w = (unsigned)t8[6] | ((unsigned)t8[7] << 16);
    *(u32x4*)(&ws[f * 512 + l * 8]) = p;
}

// load 8 B-frags (one 128-col x 128-k chunk for this wave) global->VGPR
__device__ __forceinline__ void ldB8(const unsigned short* __restrict__ ws2,
                                     int fbase, int KS, int cb0, int ks0,
                                     int lane, bf16x8 (&d)[8]) {
#pragma unroll
    for (int ks = 0; ks < 4; ks++)
#pragma unroll
        for (int n = 0; n < 2; n++)
            d[ks * 2 + n] = *(const bf16x8*)(&ws2[fbase + ((cb0 + n) * KS + ks0 + ks) * 512 + lane * 8]);
}

// one 128-k chunk of MFMA with A from LDS, B from regs
__device__ __forceinline__ void mmA_lds(const unsigned short* __restrict__ A,
                                        int astride, int akoff, const bf16x8 (&b)[8],
                                        int lr, int lk, int wm, f32x4 (&acc)[2][2]) {
#pragma unroll
    for (int ks = 0; ks < 4; ks++) {
        bf16x8 a[2];
#pragma unroll
        for (int m = 0; m < 2; m++) {
            int row = wm * 32 + m * 16 + lr;
            a[m] = *(const bf16x8*)(&A[SWZ(row * astride + akoff + ks * 32 + lk, row)]);
        }
#pragma unroll
        for (int m = 0; m < 2; m++)
#pragma unroll
            for (int n = 0; n < 2; n++)
                acc[m][n] = __builtin_amdgcn_mfma_f32_16x16x32_bf16(a[m], b[ks * 2 + n], acc[m][n], 0, 0, 0);
    }
}

template<bool RELU>
__device__ __forceinline__ void epi_store(unsigned short* dst, int dstride, int colbase,
                                          const f32x4 (&acc)[2][2], const float (&bias)[2],
                                          int lr, int lq, int wm, int wn) {
#pragma unroll
    for (int n = 0; n < 2; n++) {
        int col = colbase + wn * 32 + n * 16 + lr;
#pragma unroll
        for (int m = 0; m < 2; m++)
#pragma unroll
            for (int r = 0; r < 4; r++) {
                int row = wm * 32 + m * 16 + lq + r;
                float v = acc[m][n][r] + bias[n];
                if (RELU) v = fmaxf(v, 0.0f);
                dst[SWZ(row * dstride + col, row)] = f2bfc(v);
            }
    }
}

// ---------------------------------------------------------------------------
// kmain: one block per l, 512 threads (8 waves = 2m x 4n). LDS 96KB:
// h1 64K | xs 16K | cmb 16K. B streams global->VGPR double-buffered
// (bqA/bqB, 64 VGPR); A from LDS; only 7 barriers total.
// ---------------------------------------------------------------------------
__global__ __launch_bounds__(512, 2) void kmain(
    const float* __restrict__ x,
    const float* __restrict__ b1, const float* __restrict__ b2,
    const float* __restrict__ b3, const float* __restrict__ b4,
    const unsigned short* __restrict__ ws, float* __restrict__ out) {

    __shared__ __align__(16) unsigned char smem[98304];
    unsigned short* h1  = (unsigned short*)smem;             // 64KB [64][512]
    unsigned short* xs  = (unsigned short*)(smem + 65536);   // 16KB [64][128]
    unsigned short* cmb = (unsigned short*)(smem + 81920);   // 16KB [64][128]
    // overlays
    float* pm1  = (float*)smem;                // [32][128] in h1
    float* pm2  = pm1 + 4096;
    int*   pi1  = (int*)(pm2 + 4096);
    float* l2m1 = (float*)(smem + 49152);      // [4][128] in h1 tail
    float* l2m2 = l2m1 + 512;
    int*   l2i  = (int*)(l2m2 + 512);
    float* fm1  = (float*)(smem + 81920);      // [128] in cmb (dead until G2 epi)
    float* fm2  = fm1 + 128;
    int*   fi   = (int*)(fm2 + 128);
    float* fbuf = (float*)(smem + 65536);      // 32KB fp32 [64][128] over xs+cmb (G4 epi)

    const int tid  = threadIdx.x;
    const int lane = tid & 63;
    const int wid  = tid >> 6;                 // 0..7
    const int wm   = wid >> 2;                 // 0..1
    const int wn   = wid & 3;                  // 0..3
    const int l    = blockIdx.x;
    const int lr   = lane & 15;
    const int lk   = (lane >> 4) << 3;
    const int lq   = (lane >> 4) << 2;
    const float* xg = x + l * 64 * 128;

    bf16x8 bqA[8], bqB[8];
    // earliest possible issue: G1 chunk 0 B-frags (latency hides under P0-P2)
    ldB8(ws, 0, 4, 0 * 8 + wn * 2, 0, lane, bqA);

    float bias1v[8], bias3v[8], bias2v[2], bias4v[2];
#pragma unroll
    for (int c = 0; c < 4; c++)
#pragma unroll
        for (int n = 0; n < 2; n++) {
            bias1v[c * 2 + n] = b1[c * 128 + wn * 32 + n * 16 + lr];
            bias3v[c * 2 + n] = b3[c * 128 + wn * 32 + n * 16 + lr];
        }
#pragma unroll
    for (int n = 0; n < 2; n++) {
        bias2v[n] = b2[wn * 32 + n * 16 + lr];
        bias4v[n] = b4[wn * 32 + n * 16 + lr];
    }

    // ---- P0: stage x -> xs (bf16, swizzled) + register top-2 over 2 rows ----
    const int rp   = tid >> 4;                 // 0..31
    const int col0 = (tid & 15) * 8;
    {
        float m1[8], m2[8]; int i1[8];
#pragma unroll
        for (int e = 0; e < 8; e++) { m1[e] = -3.4e38f; m2[e] = -3.4e38f; i1[e] = -1; }
#pragma unroll
        for (int it = 0; it < 2; it++) {
            int row  = rp + it * 32;
            int base = row * 128 + col0;
            float4v v0 = *(const float4v*)(xg + base);
            float4v v1 = *(const float4v*)(xg + base + 4);
            float v[8] = {v0.x, v0.y, v0.z, v0.w, v1.x, v1.y, v1.z, v1.w};
            unsigned short t8[8];
#pragma unroll
            for (int e = 0; e < 8; e++) {
                t8[e] = f2bfc(v[e]);
                if (v[e] > m1[e]) { m2[e] = m1[e]; m1[e] = v[e]; i1[e] = row; }
                else if (v[e] > m2[e]) { m2[e] = v[e]; }
            }
            u32x4 p;
            p.x = (unsigned)t8[0] | ((unsigned)t8[1] << 16);
            p.y = (unsigned)t8[2] | ((unsigned)t8[3] << 16);
            p.z = (unsigned)t8[4] | ((unsigned)t8[5] << 16);
            p.w = (unsigned)t8[6] | ((unsigned)t8[7] << 16);
            *(u32x4*)(&xs[SWZ(base, row)]) = p;
        }
#pragma unroll
        for (int h = 0; h < 2; h++) {
            float4v q1 = {m1[h*4+0], m1[h*4+1], m1[h*4+2], m1[h*4+3]};
            float4v q2 = {m2[h*4+0], m2[h*4+1], m2[h*4+2], m2[h*4+3]};
            i32x4  qi = {i1[h*4+0], i1[h*4+1], i1[h*4+2], i1[h*4+3]};
            *(float4v*)(&pm1[rp * 128 + col0 + h * 4]) = q1;
            *(float4v*)(&pm2[rp * 128 + col0 + h * 4]) = q2;
            *(i32x4*) (&pi1[rp * 128 + col0 + h * 4]) = qi;
        }
    }
    __syncthreads();

    // ---- P1: combine 32 partials -> 4 ----
    {
        int d = tid & 127, h = tid >> 7;
        float m1 = -3.4e38f, m2 = -3.4e38f; int i1 = -1;
#pragma unroll
        for (int r = 0; r < 8; r++) {
            int q = h * 8 + r;
            float a1 = pm1[q * 128 + d], a2 = pm2[q * 128 + d]; int ai = pi1[q * 128 + d];
            if (a1 > m1) { m2 = fmaxf(m1, a2); m1 = a1; i1 = ai; }
            else         { m2 = fmaxf(m2, a1); }
        }
        l2m1[h * 128 + d] = m1; l2m2[h * 128 + d] = m2; l2i[h * 128 + d] = i1;
    }
    __syncthreads();

    // ---- P2: final top-2 -> fm1/fm2/fi ----
    if (tid < 128) {
        int d = tid;
        float m1 = l2m1[d], m2 = l2m2[d]; int i1 = l2i[d];
#pragma unroll
        for (int h = 1; h < 4; h++) {
            float a1 = l2m1[h * 128 + d], a2 = l2m2[h * 128 + d]; int ai = l2i[h * 128 + d];
            if (a1 > m1) { m2 = fmaxf(m1, a2); m1 = a1; i1 = ai; }
            else         { m2 = fmaxf(m2, a1); }
        }
        fm1[d] = m1; fm2[d] = m2; fi[d] = i1;
    }
    __syncthreads();

    // ---- build G1 A-fragments in registers ----
    bf16x8 a1f[2][4];
#pragma unroll
    for (int ks = 0; ks < 4; ks++) {
        int k0 = ks * 32 + lk;
        float4v v1a = *(const float4v*)(&fm1[k0]);
        float4v v1b = *(const float4v*)(&fm1[k0 + 4]);
        float4v v2a = *(const float4v*)(&fm2[k0]);
        float4v v2b = *(const float4v*)(&fm2[k0 + 4]);
        i32x4  ia  = *(const i32x4*)(&fi[k0]);
        i32x4  ib  = *(const i32x4*)(&fi[k0 + 4]);
        float v1[8] = {v1a.x, v1a.y, v1a.z, v1a.w, v1b.x, v1b.y, v1b.z, v1b.w};
        float v2[8] = {v2a.x, v2a.y, v2a.z, v2a.w, v2b.x, v2b.y, v2b.z, v2b.w};
        int   ii[8] = {ia.x, ia.y, ia.z, ia.w, ib.x, ib.y, ib.z, ib.w};
#pragma unroll
        for (int m = 0; m < 2; m++) {
            int j = wm * 32 + m * 16 + lr;
            unsigned short t8[8];
#pragma unroll
            for (int e = 0; e < 8; e++) {
                float s = (ii[e] == j) ? v2[e] : v1[e];
                t8[e] = f2bfc(fmaxf(s, 0.0f));
            }
            u32x4 p;
            p.x = (unsigned)t8[0] | ((unsigned)t8[1] << 16);
            p.y = (unsigned)t8[2] | ((unsigned)t8[3] << 16);
            p.z = (unsigned)t8[4] | ((unsigned)t8[5] << 16);
            p.w = (unsigned)t8[6] | ((unsigned)t8[7] << 16);
            a1f[m][ks] = __builtin_bit_cast(bf16x8, p);
        }
    }

    // ---- G1: 4 chunks, A regs, B dbuf; no barriers inside ----
#pragma unroll
    for (int c = 0; c < 4; c++) {
        bf16x8 (&cur)[8] = (c & 1) ? bqB : bqA;
        bf16x8 (&nxt)[8] = (c & 1) ? bqA : bqB;
        if (c < 3) ldB8(ws, 0, 4, (c + 1) * 8 + wn * 2, 0, lane, nxt);
        else       ldB8(ws, 65536, 16, wn * 2, 0, lane, nxt);   // G2 chunk 0
        f32x4 acc[2][2];
#pragma unroll
        for (int m = 0; m < 2; m++) { acc[m][0] = (f32x4)0.0f; acc[m][1] = (f32x4)0.0f; }
#pragma unroll
        for (int ks = 0; ks < 4; ks++)
#pragma unroll
            for (int m = 0; m < 2; m++)
#pragma unroll
                for (int n = 0; n < 2; n++)
                    acc[m][n] = __builtin_amdgcn_mfma_f32_16x16x32_bf16(a1f[m][ks], cur[ks * 2 + n], acc[m][n], 0, 0, 0);
        float bc[2] = {bias1v[c * 2 + 0], bias1v[c * 2 + 1]};
        epi_store<true>(h1, 512, c * 128, acc, bc, lr, lq, wm, wn);
    }
    __syncthreads();

    // ---- G2: 4 K-chunks over h1; acc persists; no barriers inside ----
    {
        f32x4 acc[2][2];
#pragma unroll
        for (int m = 0; m < 2; m++) { acc[m][0] = (f32x4)0.0f; acc[m][1] = (f32x4)0.0f; }
#pragma unroll
        for (int c = 0; c < 4; c++) {
            bf16x8 (&cur)[8] = (c & 1) ? bqB : bqA;
            bf16x8 (&nxt)[8] = (c & 1) ? bqA : bqB;
            if (c < 3) ldB8(ws, 65536, 16, wn * 2, (c + 1) * 4, lane, nxt);
            else       ldB8(ws, 131072, 8, 0 * 8 + wn * 2, 0, lane, nxt);  // G3 step 0
            mmA_lds(h1, 512, c * 128, cur, lr, lk, wm, acc);
        }
        epi_store<false>(cmb, 128, 0, acc, bias2v, lr, lq, wm, wn);
    }
    __syncthreads();

    // ---- G3: 8 steps (nc 0..3 x {xs-half, cmb-half}); writes h1 ----
    {
        f32x4 acc[2][2];
#pragma unroll
        for (int t = 0; t < 8; t++) {
            bf16x8 (&cur)[8] = (t & 1) ? bqB : bqA;
            bf16x8 (&nxt)[8] = (t & 1) ? bqA : bqB;
            if (t < 7) ldB8(ws, 131072, 8, ((t + 1) >> 1) * 8 + wn * 2, ((t + 1) & 1) * 4, lane, nxt);
            else       ldB8(ws, 262144, 16, wn * 2, 0, lane, nxt);  // G4 chunk 0
            if ((t & 1) == 0) {
#pragma unroll
                for (int m = 0; m < 2; m++) { acc[m][0] = (f32x4)0.0f; acc[m][1] = (f32x4)0.0f; }
            }
            mmA_lds((t & 1) ? cmb : xs, 128, 0, cur, lr, lk, wm, acc);
            if (t & 1) {
                int nc = t >> 1;
                float bc[2] = {bias3v[nc * 2 + 0], bias3v[nc * 2 + 1]};
                epi_store<true>(h1, 512, nc * 128, acc, bc, lr, lq, wm, wn);
            }
        }
    }
    __syncthreads();

    // ---- G4: 4 K-chunks over h1; epi -> fbuf (fp32, over xs+cmb) ----
    float4v xr[4];
    {
        f32x4 acc[2][2];
#pragma unroll
        for (int m = 0; m < 2; m++) { acc[m][0] = (f32x4)0.0f; acc[m][1] = (f32x4)0.0f; }
#pragma unroll
        for (int it = 0; it < 4; it++) {
            int f = tid + it * 512;
            xr[it] = *(const float4v*)(&xg[(f >> 5) * 128 + (f & 31) * 4]);
        }
#pragma unroll
        for (int c = 0; c < 4; c++) {
            bf16x8 (&cur)[8] = (c & 1) ? bqB : bqA;
            bf16x8 (&nxt)[8] = (c & 1) ? bqA : bqB;
            if (c < 3) ldB8(ws, 262144, 16, wn * 2, (c + 1) * 4, lane, nxt);
            mmA_lds(h1, 512, c * 128, cur, lr, lk, wm, acc);
        }
#pragma unroll
        for (int n = 0; n < 2; n++) {
            int col = wn * 32 + n * 16 + lr;
#pragma unroll
            for (int m = 0; m < 2; m++)
#pragma unroll
                for (int r = 0; r < 4; r++) {
                    int row = wm * 32 + m * 16 + lq + r;
                    fbuf[row * 128 + col] = acc[m][n][r] + bias4v[n];
                }
        }
    }
    __syncthreads();

    // ---- coalesced residual + fp32 store ----
#pragma unroll
    for (int it = 0; it < 4; it++) {
        int f = tid + it * 512;
        int row = f >> 5, c0 = (f & 31) * 4;
        float4v h = *(const float4v*)(&fbuf[row * 128 + c0]);
        float4v o;
        o.x = h.x + xr[it].x; o.y = h.y + xr[it].y;
        o.z = h.z + xr[it].z; o.w = h.w + xr[it].w;
        *(float4v*)(&out[(l * 64 + row) * 128 + c0]) = o;
    }
}

extern "C" void kernel_launch(void* const* d_in, const int* in_sizes, int n_in,
                              void* d_out, int out_size, void* d_ws, size_t ws_size,
                              hipStream_t stream) {
    const float* x  = (const float*)d_in[0];
    const float* W1 = (const float*)d_in[1];
    const float* b1 = (const float*)d_in[2];
    const float* W2 = (const float*)d_in[3];
    const float* b2 = (const float*)d_in[4];
    const float* W3 = (const float*)d_in[5];
    const float* b3 = (const float*)d_in[6];
    const float* W4 = (const float*)d_in[7];
    const float* b4 = (const float*)d_in[8];
    unsigned short* ws = (unsigned short*)d_ws;
    float* out = (float*)d_out;

    kprep<<<160, 256, 0, stream>>>(W1, W2, W3, W4, ws);
    kmain<<<256, 512, 0, stream>>>(x, b1, b2, b3, b4, ws, out);
}